// Round 14
// baseline (481.296 us; speedup 1.0000x reference)
//
#include <hip/hip_runtime.h>
#include <hip/hip_bf16.h>

#define N_NODES 50000
#define N_EDGES 800000
#define E_TOT   (N_EDGES + N_NODES)   /* 850000: edges + self-loops */
#define IN_CH   128
#define HID     64
#define HEADS   4
#define F1      256                   /* HEADS*HID */
#define OUT_CH  12
#define NEG_SLOPE 0.2f
#define CAP     256                   /* cached edges per node (deg ~Poisson(17); overflow has fallback) */

typedef __attribute__((ext_vector_type(8))) short  bf16x8;
typedef __attribute__((ext_vector_type(4))) float  f32x4;

__device__ __forceinline__ float leaky(float x) { return x > 0.f ? x : NEG_SLOPE * x; }

// f32 -> bf16 round-to-nearest-even
__device__ __forceinline__ unsigned short tob(float f) {
    unsigned u = __float_as_uint(f);
    u += 0x7fffu + ((u >> 16) & 1u);
    return (unsigned short)(u >> 16);
}
__device__ __forceinline__ float fromb(unsigned short s) {
    return __uint_as_float(((unsigned)s) << 16);
}

// async global->LDS, 16 B per lane; LDS dest = wave-uniform base + lane*16
typedef __attribute__((address_space(3))) unsigned int        lds_u32;
typedef const __attribute__((address_space(1))) unsigned int  glb_u32;
__device__ __forceinline__ void gload16(const void* g, void* l) {
    __builtin_amdgcn_global_load_lds((glb_u32*)g, (lds_u32*)l, 16, 0, 0);
}

// ---------------- CSR build ----------------
__global__ void k_zero(int* p, int n) {
    int i = blockIdx.x * blockDim.x + threadIdx.x;
    if (i < n) p[i] = 0;
}

// zero the two guard rows around hB (for conv's n-1 / n+1 reads)
__global__ void k_guard(unsigned int* front, unsigned int* back) {
    int i = threadIdx.x;
    if (i < 128) front[i] = 0;
    else         back[i - 128] = 0;
}

__global__ void k_count(const int* __restrict__ ei, int* __restrict__ counts) {
    int i = blockIdx.x * blockDim.x + threadIdx.x;
    if (i >= E_TOT) return;
    int dst = (i < N_EDGES) ? ei[N_EDGES + i] : (i - N_EDGES);
    atomicAdd(&counts[dst], 1);
}

// single-block exclusive scan, shuffle-based
__global__ __launch_bounds__(1024) void k_scan(const int* __restrict__ counts,
                                               int* __restrict__ rowptr,
                                               int* __restrict__ cursor) {
    __shared__ int wsum[16];
    __shared__ int carrysh;
    const int lane = threadIdx.x & 63, w = threadIdx.x >> 6;
    if (threadIdx.x == 0) carrysh = 0;
    __syncthreads();
    for (int base = 0; base < N_NODES; base += 1024) {
        int i = base + threadIdx.x;
        int v = (i < N_NODES) ? counts[i] : 0;
        int s = v;
        #pragma unroll
        for (int off = 1; off < 64; off <<= 1) {
            int t = __shfl_up(s, off);
            if (lane >= off) s += t;
        }
        if (lane == 63) wsum[w] = s;
        __syncthreads();
        int woff = 0;
        for (int j = 0; j < w; ++j) woff += wsum[j];
        int incl = carrysh + woff + s;
        if (i < N_NODES) { rowptr[i] = incl - v; cursor[i] = incl - v; }
        __syncthreads();
        if (threadIdx.x == 1023) carrysh = incl;
        __syncthreads();
    }
    if (threadIdx.x == 0) rowptr[N_NODES] = carrysh;
}

__global__ void k_fill(const int* __restrict__ ei, int* __restrict__ cursor,
                       int* __restrict__ csr_src) {
    int i = blockIdx.x * blockDim.x + threadIdx.x;
    if (i >= E_TOT) return;
    int src, dst;
    if (i < N_EDGES) { src = ei[i]; dst = ei[N_EDGES + i]; }
    else             { src = dst = i - N_EDGES; }
    int pos = atomicAdd(&cursor[dst], 1);
    csr_src[pos] = src;
}

// ---------------- casts / weight prep ----------------
__global__ void k_cast4(const float* __restrict__ in, unsigned short* __restrict__ out, int n4) {
    int i = blockIdx.x * blockDim.x + threadIdx.x;
    if (i >= n4) return;
    float4 v = *(const float4*)&in[i * 4];
    ushort4 o;
    o.x = tob(v.x); o.y = tob(v.y); o.z = tob(v.z); o.w = tob(v.w);
    *(ushort4*)&out[i * 4] = o;
}

// WT[n*K+k] = bf16(W[k*N+n]); W is K x N row-major
__global__ void k_prep_wt(const float* __restrict__ W, unsigned short* __restrict__ WT,
                          int K, int N) {
    int idx = blockIdx.x * blockDim.x + threadIdx.x;
    if (idx >= K * N) return;
    int n = idx / K, k = idx % K;
    WT[idx] = tob(W[(size_t)k * N + n]);
}

// conv weights CW[o][c][k] (64 x 256 x 3) -> BT[o][kseg*256+c]  (64 x 768)
__global__ void k_prep_cw(const float* __restrict__ CW, unsigned short* __restrict__ BT) {
    int idx = blockIdx.x * blockDim.x + threadIdx.x;
    if (idx >= 64 * 768) return;
    int o = idx / 768, kk = idx % 768;
    int kseg = kk >> 8, c = kk & 255;
    BT[idx] = tob(CW[((size_t)o * 256 + c) * 3 + kseg]);
}

// ---------------- bf16 MFMA GEMM: C[M,F1] = A[M,K] @ BT[F1,K]^T ----------------
// 128x128 tile, BK=32, 4 waves (2x2), global_load_lds width-16 staging, linear LDS.
__global__ __launch_bounds__(256) void k_gemm_bf16(const unsigned short* __restrict__ A,
                                                   const unsigned short* __restrict__ BT,
                                                   unsigned short* __restrict__ C,
                                                   int M, int K) {
    __shared__ unsigned short As[128][32];   // linear (gload_lds requirement)
    __shared__ unsigned short Bs[128][32];
    const int t    = threadIdx.x;
    const int lane = t & 63, wave = t >> 6;
    const int wr = wave >> 1, wc = wave & 1;
    const int row0 = blockIdx.y * 128, col0 = blockIdx.x * 128;
    const int l15 = lane & 15, kg = lane >> 4;

    const int srow = (wave << 4) + (lane >> 2);
    const int sseg = (lane & 3) * 8;             // shorts
    int ar0 = row0 + srow;      if (ar0 >= M) ar0 = M - 1;   // clamp: OOB rows discarded at C-write
    int ar1 = row0 + srow + 64; if (ar1 >= M) ar1 = M - 1;
    const int br0 = col0 + srow, br1 = col0 + srow + 64;     // always < F1
    unsigned short* ldsA = &As[0][0];
    unsigned short* ldsB = &Bs[0][0];
    const int lofs0 = wave * 512, lofs1 = 2048 + wave * 512; // shorts (1024 B / wave issue)

    f32x4 acc[4][4];
    #pragma unroll
    for (int m = 0; m < 4; ++m)
        #pragma unroll
        for (int n = 0; n < 4; ++n) acc[m][n] = 0.f;

    for (int k0 = 0; k0 < K; k0 += 32) {
        gload16(&A [(size_t)ar0 * K + k0 + sseg], ldsA + lofs0);
        gload16(&A [(size_t)ar1 * K + k0 + sseg], ldsA + lofs1);
        gload16(&BT[(size_t)br0 * K + k0 + sseg], ldsB + lofs0);
        gload16(&BT[(size_t)br1 * K + k0 + sseg], ldsB + lofs1);
        __syncthreads();
        bf16x8 af[4], bf[4];
        #pragma unroll
        for (int m = 0; m < 4; ++m) af[m] = *(const bf16x8*)&As[wr * 64 + m * 16 + l15][kg * 8];
        #pragma unroll
        for (int n = 0; n < 4; ++n) bf[n] = *(const bf16x8*)&Bs[wc * 64 + n * 16 + l15][kg * 8];
        #pragma unroll
        for (int m = 0; m < 4; ++m)
            #pragma unroll
            for (int n = 0; n < 4; ++n)
                acc[m][n] = __builtin_amdgcn_mfma_f32_16x16x32_bf16(af[m], bf[n], acc[m][n], 0, 0, 0);
        __syncthreads();
    }
    #pragma unroll
    for (int m = 0; m < 4; ++m) {
        #pragma unroll
        for (int j = 0; j < 4; ++j) {
            int row = row0 + wr * 64 + m * 16 + (lane >> 4) * 4 + j;
            if (row < M) {
                #pragma unroll
                for (int n = 0; n < 4; ++n)
                    C[(size_t)row * F1 + col0 + wc * 64 + n * 16 + l15] = tob(acc[m][n][j]);
            }
        }
    }
}

// ---------------- attention coefficients from bf16 h ----------------
__global__ __launch_bounds__(256) void k_attn(const unsigned short* __restrict__ H,
                                              const float* __restrict__ a_src,
                                              const float* __restrict__ a_dst,
                                              float* __restrict__ oS,
                                              float* __restrict__ oD) {
    int lane = threadIdx.x & 63, wid = threadIdx.x >> 6;
    int node = blockIdx.x * 4 + wid;
    int head = lane >> 4, cc = (lane & 15) * 4;
    ushort4 hv4 = *(const ushort4*)&H[(size_t)node * F1 + lane * 4];
    float h0 = fromb(hv4.x), h1 = fromb(hv4.y), h2 = fromb(hv4.z), h3 = fromb(hv4.w);
    float4 sv = *(const float4*)&a_src[head * HID + cc];
    float4 dv = *(const float4*)&a_dst[head * HID + cc];
    float s = h0 * sv.x + h1 * sv.y + h2 * sv.z + h3 * sv.w;
    float d = h0 * dv.x + h1 * dv.y + h2 * dv.z + h3 * dv.w;
    #pragma unroll
    for (int off = 1; off < 16; off <<= 1) {
        s += __shfl_xor(s, off);
        d += __shfl_xor(d, off);
    }
    if ((lane & 15) == 0) { oS[node * 4 + head] = s; oD[node * 4 + head] = d; }
}

// ---------------- per-destination softmax + aggregate (one wave per node) ----------------
// Two-pass softmax; phase 2 gathers with 4 edges in flight (4 lane-groups x 16 lanes,
// 32B per lane) and cross-group shuffle reduce. Normalization deferred to epilogue.
__global__ __launch_bounds__(256) void k_agg(const unsigned short* __restrict__ H,
                                             const float* __restrict__ aS,
                                             const float* __restrict__ aD,
                                             const int* __restrict__ rowptr,
                                             const int* __restrict__ csr,
                                             const float* __restrict__ bias,
                                             unsigned short* __restrict__ O) {
    __shared__ float wlds[4][CAP][4];   // 16 KB/block
    int lane = threadIdx.x & 63, wid = threadIdx.x >> 6;
    int node = blockIdx.x * 4 + wid;
    int beg = rowptr[node], end = rowptr[node + 1];
    int deg = end - beg;

    float4 adv = *(const float4*)&aD[node * 4];
    float ad[4] = { adv.x, adv.y, adv.z, adv.w };
    float m[4] = { -1e30f, -1e30f, -1e30f, -1e30f };

    // phase 1: e -> LDS, track max only (no exp)
    for (int j = beg + lane, idx = lane; j < end; j += 64, idx += 64) {
        int src = csr[j];
        float4 asv = *(const float4*)&aS[src * 4];
        float4 e4;
        e4.x = leaky(asv.x + ad[0]);
        e4.y = leaky(asv.y + ad[1]);
        e4.z = leaky(asv.z + ad[2]);
        e4.w = leaky(asv.w + ad[3]);
        m[0] = fmaxf(m[0], e4.x); m[1] = fmaxf(m[1], e4.y);
        m[2] = fmaxf(m[2], e4.z); m[3] = fmaxf(m[3], e4.w);
        if (idx < CAP) *(float4*)&wlds[wid][idx][0] = e4;
    }
    #pragma unroll
    for (int off = 1; off < 64; off <<= 1) {
        #pragma unroll
        for (int h = 0; h < 4; ++h) m[h] = fmaxf(m[h], __shfl_xor(m[h], off));
    }

    // phase 1.5: w = exp(e - M) in place, accumulate s
    float s[4] = { 0.f, 0.f, 0.f, 0.f };
    int degc = deg < CAP ? deg : CAP;
    for (int idx = lane; idx < degc; idx += 64) {
        float4 e4 = *(float4*)&wlds[wid][idx][0];
        float4 w4;
        w4.x = __expf(e4.x - m[0]); w4.y = __expf(e4.y - m[1]);
        w4.z = __expf(e4.z - m[2]); w4.w = __expf(e4.w - m[3]);
        s[0] += w4.x; s[1] += w4.y; s[2] += w4.z; s[3] += w4.w;
        *(float4*)&wlds[wid][idx][0] = w4;
    }
    for (int j = beg + CAP + lane; j < end; j += 64) {   // overflow: count into s
        int src = csr[j];
        float4 asv = *(const float4*)&aS[src * 4];
        s[0] += __expf(leaky(asv.x + ad[0]) - m[0]);
        s[1] += __expf(leaky(asv.y + ad[1]) - m[1]);
        s[2] += __expf(leaky(asv.z + ad[2]) - m[2]);
        s[3] += __expf(leaky(asv.w + ad[3]) - m[3]);
    }
    #pragma unroll
    for (int off = 1; off < 64; off <<= 1) {
        #pragma unroll
        for (int h = 0; h < 4; ++h) s[h] += __shfl_xor(s[h], off);
    }

    // phase 2: 4 edges in flight; group g handles idx % 4 == g; lane covers 16 channels
    const int g   = lane >> 4;
    const int l15 = lane & 15;
    const int hl  = l15 >> 2;            // head of this lane's 16-channel chunk
    float acc[16];
    #pragma unroll
    for (int k = 0; k < 16; ++k) acc[k] = 0.f;

    for (int idx = g; idx < degc; idx += 4) {
        int src = csr[beg + idx];
        float w = wlds[wid][idx][hl];
        const unsigned short* hp = &H[(size_t)src * F1 + l15 * 16];
        bf16x8 h0 = *(const bf16x8*)hp;
        bf16x8 h1 = *(const bf16x8*)(hp + 8);
        #pragma unroll
        for (int k = 0; k < 8; ++k) acc[k]     += w * fromb((unsigned short)h0[k]);
        #pragma unroll
        for (int k = 0; k < 8; ++k) acc[k + 8] += w * fromb((unsigned short)h1[k]);
    }
    for (int idx = CAP + g; idx < deg; idx += 4) {   // overflow fallback (virtually never taken)
        int src = csr[beg + idx];
        float as4[4];
        *(float4*)as4 = *(const float4*)&aS[src * 4];
        float w = __expf(leaky(as4[hl] + ad[hl]) - m[hl]);
        const unsigned short* hp = &H[(size_t)src * F1 + l15 * 16];
        bf16x8 h0 = *(const bf16x8*)hp;
        bf16x8 h1 = *(const bf16x8*)(hp + 8);
        #pragma unroll
        for (int k = 0; k < 8; ++k) acc[k]     += w * fromb((unsigned short)h0[k]);
        #pragma unroll
        for (int k = 0; k < 8; ++k) acc[k + 8] += w * fromb((unsigned short)h1[k]);
    }
    // cross-group reduce: every lane ends with full sums for its 16 channels
    #pragma unroll
    for (int off = 16; off < 64; off <<= 1) {
        #pragma unroll
        for (int k = 0; k < 16; ++k) acc[k] += __shfl_xor(acc[k], off);
    }

    if (g == 0) {
        float invh = 1.f / (s[hl] + 1e-16f);
        const float* bp = &bias[l15 * 16];
        unsigned short ob[16];
        #pragma unroll
        for (int k = 0; k < 16; ++k) ob[k] = tob(fmaxf(acc[k] * invh + bp[k], 0.f));
        unsigned short* op = &O[(size_t)node * F1 + l15 * 16];
        *(uint4*)op       = *(uint4*)&ob[0];
        *(uint4*)(op + 8) = *(uint4*)&ob[8];
    }
}

// ---------------- Conv1d as MFMA GEMM: Y[M,64] = A[M,768] @ BcT[64,768]^T ----------------
// A[n, kseg*256+c] = H[n+kseg-1, c]; H has zeroed guard rows at -1 and N (hB padding).
__global__ __launch_bounds__(256) void k_conv(const unsigned short* __restrict__ H,
                                              const unsigned short* __restrict__ BcT,
                                              const float* __restrict__ CB,
                                              float* __restrict__ Y) {
    __shared__ unsigned short As[128][32];
    __shared__ unsigned short Bs[64][32];
    const int t    = threadIdx.x;
    const int lane = t & 63, wave = t >> 6;     // 4 waves stacked on M
    const int row0 = blockIdx.x * 128;
    const int l15 = lane & 15, kg = lane >> 4;

    const int srow = (wave << 4) + (lane >> 2);
    const int sseg = (lane & 3) * 8;
    unsigned short* ldsA = &As[0][0];
    unsigned short* ldsB = &Bs[0][0];
    const int lofs0 = wave * 512, lofs1 = 2048 + wave * 512;

    f32x4 acc[2][4];
    #pragma unroll
    for (int m = 0; m < 2; ++m)
        #pragma unroll
        for (int n = 0; n < 4; ++n) acc[m][n] = 0.f;

    for (int k0 = 0; k0 < 768; k0 += 32) {
        int kseg  = k0 >> 8;
        int cbase = (k0 & 255) + sseg;
        int gr0 = row0 + srow + kseg - 1;      // >= -1 (guard row)
        int gr1 = gr0 + 64;
        if (gr1 > N_NODES) gr1 = N_NODES;      // clamp to back guard (zeros; rows discarded anyway)
        gload16(H + (ptrdiff_t)gr0 * F1 + cbase, ldsA + lofs0);
        gload16(H + (ptrdiff_t)gr1 * F1 + cbase, ldsA + lofs1);
        { // B tile: 64x32, one issue per wave
            int brow = srow;                   // < 64
            gload16(&BcT[(size_t)brow * 768 + k0 + sseg], ldsB + lofs0);
        }
        __syncthreads();
        bf16x8 af[2], bf[4];
        #pragma unroll
        for (int m = 0; m < 2; ++m) af[m] = *(const bf16x8*)&As[wave * 32 + m * 16 + l15][kg * 8];
        #pragma unroll
        for (int n = 0; n < 4; ++n) bf[n] = *(const bf16x8*)&Bs[n * 16 + l15][kg * 8];
        #pragma unroll
        for (int m = 0; m < 2; ++m)
            #pragma unroll
            for (int n = 0; n < 4; ++n)
                acc[m][n] = __builtin_amdgcn_mfma_f32_16x16x32_bf16(af[m], bf[n], acc[m][n], 0, 0, 0);
        __syncthreads();
    }
    #pragma unroll
    for (int m = 0; m < 2; ++m) {
        #pragma unroll
        for (int j = 0; j < 4; ++j) {
            int row = row0 + wave * 32 + m * 16 + (lane >> 4) * 4 + j;
            if (row < N_NODES) {
                #pragma unroll
                for (int n = 0; n < 4; ++n) {
                    int col = n * 16 + l15;
                    Y[(size_t)row * HID + col] = fmaxf(acc[m][n][j] + CB[col], 0.f);
                }
            }
        }
    }
}

// ---------------- final linear ----------------
__global__ __launch_bounds__(256) void k_lin(const float* __restrict__ Y,
                                             const float* __restrict__ LW,
                                             const float* __restrict__ LB,
                                             float* __restrict__ OUT) {
    __shared__ float w[64][12];
    __shared__ float b[12];
    for (int i = threadIdx.x; i < 64 * 12; i += 256) w[i / 12][i % 12] = LW[i];
    if (threadIdx.x < 12) b[threadIdx.x] = LB[threadIdx.x];
    __syncthreads();
    int n = blockIdx.x * 256 + threadIdx.x;
    if (n >= N_NODES) return;
    float acc[12];
    #pragma unroll
    for (int o = 0; o < 12; ++o) acc[o] = b[o];
    for (int c = 0; c < 64; c += 4) {
        float4 yv = *(const float4*)&Y[(size_t)n * HID + c];
        #pragma unroll
        for (int o = 0; o < 12; ++o)
            acc[o] += yv.x * w[c][o] + yv.y * w[c + 1][o]
                    + yv.z * w[c + 2][o] + yv.w * w[c + 3][o];
    }
    #pragma unroll
    for (int o = 0; o < 12; ++o) OUT[(size_t)n * OUT_CH + o] = acc[o];
}

extern "C" void kernel_launch(void* const* d_in, const int* in_sizes, int n_in,
                              void* d_out, int out_size, void* d_ws, size_t ws_size,
                              hipStream_t stream) {
    const float* x   = (const float*)d_in[0];
    const int*   ei  = (const int*)d_in[1];
    const float* W1  = (const float*)d_in[2];
    const float* as1 = (const float*)d_in[3];
    const float* ad1 = (const float*)d_in[4];
    const float* b1  = (const float*)d_in[5];
    const float* W2  = (const float*)d_in[6];
    const float* as2 = (const float*)d_in[7];
    const float* ad2 = (const float*)d_in[8];
    const float* b2  = (const float*)d_in[9];
    const float* cw  = (const float*)d_in[10];
    const float* cb  = (const float*)d_in[11];
    const float* lw  = (const float*)d_in[12];
    const float* lb  = (const float*)d_in[13];
    float* out = (float*)d_out;

    char* ws = (char*)d_ws;
    size_t off = 0;
    auto alloc = [&](size_t bytes) -> void* {
        off = (off + 255) & ~(size_t)255;
        void* p = ws + off;
        off += bytes;
        return p;
    };
    unsigned short* hA  = (unsigned short*)alloc((size_t)N_NODES * F1 * 2);        // gemm out (h)
    unsigned short* hBg = (unsigned short*)alloc((size_t)(N_NODES + 2) * F1 * 2);  // agg out + guards
    unsigned short* hB  = hBg + F1;                                                // row 0 of real data
    unsigned short* xb  = (unsigned short*)alloc((size_t)N_NODES * IN_CH * 2);
    unsigned short* wt1 = (unsigned short*)alloc((size_t)F1 * IN_CH * 2);
    unsigned short* wt2 = (unsigned short*)alloc((size_t)F1 * F1 * 2);
    unsigned short* cwt = (unsigned short*)alloc((size_t)HID * 768 * 2);
    float* alS    = (float*)alloc((size_t)N_NODES * 4 * 4);
    float* alD    = (float*)alloc((size_t)N_NODES * 4 * 4);
    int*   counts = (int*)  alloc((size_t)N_NODES * 4);
    int*   rowptr = (int*)  alloc((size_t)(N_NODES + 1) * 4);
    int*   cursor = (int*)  alloc((size_t)N_NODES * 4);
    int*   csr    = (int*)  alloc((size_t)E_TOT * 4);
    float* y      = (float*)alloc((size_t)N_NODES * HID * 4);

    // CSR build + guard zeroing
    k_zero <<<(N_NODES + 255) / 256, 256, 0, stream>>>(counts, N_NODES);
    k_guard<<<1, 256, 0, stream>>>((unsigned int*)hBg,
                                   (unsigned int*)(hBg + (size_t)(N_NODES + 1) * F1));
    k_count<<<(E_TOT + 255) / 256, 256, 0, stream>>>(ei, counts);
    k_scan <<<1, 1024, 0, stream>>>(counts, rowptr, cursor);
    k_fill <<<(E_TOT + 255) / 256, 256, 0, stream>>>(ei, cursor, csr);

    // casts / weight prep
    k_cast4 <<<(N_NODES * IN_CH / 4 + 255) / 256, 256, 0, stream>>>(x, xb, N_NODES * IN_CH / 4);
    k_prep_wt<<<(IN_CH * F1 + 255) / 256, 256, 0, stream>>>(W1, wt1, IN_CH, F1);
    k_prep_wt<<<(F1 * F1 + 255) / 256, 256, 0, stream>>>(W2, wt2, F1, F1);
    k_prep_cw<<<(HID * 768 + 255) / 256, 256, 0, stream>>>(cw, cwt);

    dim3 gg(F1 / 128, (N_NODES + 127) / 128);
    // layer 1
    k_gemm_bf16<<<gg, 256, 0, stream>>>(xb, wt1, hA, N_NODES, IN_CH);
    k_attn<<<N_NODES / 4, 256, 0, stream>>>(hA, as1, ad1, alS, alD);
    k_agg <<<N_NODES / 4, 256, 0, stream>>>(hA, alS, alD, rowptr, csr, b1, hB);
    // layer 2
    k_gemm_bf16<<<gg, 256, 0, stream>>>(hB, wt2, hA, N_NODES, F1);
    k_attn<<<N_NODES / 4, 256, 0, stream>>>(hA, as2, ad2, alS, alD);
    k_agg <<<N_NODES / 4, 256, 0, stream>>>(hA, alS, alD, rowptr, csr, b2, hB);
    // conv + final linear
    k_conv<<<(N_NODES + 127) / 128, 256, 0, stream>>>(hB, cwt, cb, y);
    k_lin <<<(N_NODES + 255) / 256, 256, 0, stream>>>(y, lw, lb, out);
}